// Round 15
// baseline (119.859 us; speedup 1.0000x reference)
//
#include <hip/hip_runtime.h>

#define DD 256
#define BB 8
#define SS 1024
#define XSTRIDE 264   // f16 elems per LDS row (528 B, 16B-aligned)

// ws layout per layer (bytes): Mtab 131072 | Ptab 131072 | Itab 262144 = 524288
#define LAYER_BYTES 524288
#define PTAB_OFF    131072
#define ITAB_OFF    262144
#define WS_NEEDED   (2 * LAYER_BYTES)

typedef _Float16 half8  __attribute__((ext_vector_type(8)));
typedef _Float16 half2t __attribute__((ext_vector_type(2)));
typedef __fp16   fp16x2 __attribute__((ext_vector_type(2)));
typedef __attribute__((ext_vector_type(4))) float float4v;

typedef union { half8 h; half2t h2[4]; } hu;

__device__ __forceinline__ half2t pkrtz(float a, float b) {
    union { fp16x2 f; half2t h; } cv;
    cv.f = __builtin_amdgcn_cvt_pkrtz(a, b);
    return cv.h;
}

// Fragment-ordered tables: gi = (kt*16 + wt)*64 + lane, lane = quad*16+l15,
// n = 16*wt + l15, j0 = kt*32 + quad*8:
//   Mtab[gi] = M[n][j0..j0+7] f16, Ptab[gi] = P[n][j0..j0+7] f16,
//   Itab[2gi..] = 1/(n*256 + j0 + e + 2) f32, e=0..7
__global__ void build_tabs(const float* __restrict__ M1, const float* __restrict__ P1,
                           const float* __restrict__ M2, const float* __restrict__ P2,
                           char* __restrict__ ws)
{
    int gid   = blockIdx.x * 256 + threadIdx.x;   // 0..16383
    int layer = gid >> 13;
    int gi    = gid & 8191;
    int idx   = gi >> 6;
    int lane  = gi & 63;
    int kt    = idx >> 4;
    int wt    = idx & 15;
    int l15   = lane & 15, quad = lane >> 4;
    int n     = 16 * wt + l15;
    int j0    = kt * 32 + quad * 8;

    const float* Msrc = layer ? M2 : M1;
    const float* Psrc = layer ? P2 : P1;

    hu mh, ph;
    float iv[8];
    #pragma unroll
    for (int e = 0; e < 4; ++e) {
        mh.h2[e] = pkrtz(Msrc[(size_t)n * DD + j0 + 2 * e],
                         Msrc[(size_t)n * DD + j0 + 2 * e + 1]);
        ph.h2[e] = pkrtz(Psrc[(size_t)n * DD + j0 + 2 * e],
                         Psrc[(size_t)n * DD + j0 + 2 * e + 1]);
        iv[2 * e]     = 1.0f / (float)(n * DD + j0 + 2 * e + 2);
        iv[2 * e + 1] = 1.0f / (float)(n * DD + j0 + 2 * e + 3);
    }
    char* base = ws + (size_t)layer * LAYER_BYTES;
    ((half8*)base)[gi]              = mh.h;
    ((half8*)(base + PTAB_OFF))[gi] = ph.h;
    float4* it = (float4*)(base + ITAB_OFF);
    it[2 * gi]     = make_float4(iv[0], iv[1], iv[2], iv[3]);
    it[2 * gi + 1] = make_float4(iv[4], iv[5], iv[6], iv[7]);
}

// exact-path W-gen + dual MFMA for one (kt,t): bit-identical to R10 numerics
__device__ __forceinline__ void pb_comp(const half8& a, const hu& pv,
                                        const float4& i0, const float4& i1,
                                        float k0, float k1,
                                        float4v& acc0, float4v& acc1)
{
    const float iv[8] = {i0.x, i0.y, i0.z, i0.w, i1.x, i1.y, i1.z, i1.w};
    hu b0, b1;
    #pragma unroll
    for (int ep = 0; ep < 4; ++ep) {
        float ia = iv[2 * ep], ib = iv[2 * ep + 1];
        float c0a = __builtin_amdgcn_cosf(__builtin_amdgcn_fractf(k0 * ia));
        float c0b = __builtin_amdgcn_cosf(__builtin_amdgcn_fractf(k0 * ib));
        float c1a = __builtin_amdgcn_cosf(__builtin_amdgcn_fractf(k1 * ia));
        float c1b = __builtin_amdgcn_cosf(__builtin_amdgcn_fractf(k1 * ib));
        b0.h2[ep] = pv.h2[ep] * pkrtz(c0a, c0b);
        b1.h2[ep] = pv.h2[ep] * pkrtz(c1a, c1b);
    }
    acc0 = __builtin_amdgcn_mfma_f32_16x16x32_f16(a, b0.h, acc0, 0, 0, 0);
    acc1 = __builtin_amdgcn_mfma_f32_16x16x32_f16(a, b1.h, acc1, 0, 0, 0);
}

// Block = 512 threads (8 waves), s-pair per block, grid 512 (2 blocks/CU).
// Wave w owns n-tiles 2w, 2w+1. Residual in registers.
// Phase A/B: explicit depth-1 register prefetch of next-kt table data
// (loads for kt+1 issue BEFORE compute of kt) to cover L2 latency.
template<bool TABS>
__global__ __launch_bounds__(512, 4)
void fused_hierddpm(const float* __restrict__ seq,
                    const float* __restrict__ M1, const float* __restrict__ P1,
                    const float* __restrict__ g1, const float* __restrict__ be1,
                    const float* __restrict__ M2, const float* __restrict__ P2,
                    const float* __restrict__ g2, const float* __restrict__ be2,
                    const char* __restrict__ ws,
                    float* __restrict__ out)
{
    __shared__ __align__(16) _Float16 xsb[16][XSTRIDE]; // input / layer-out, f16, A-layout
    __shared__ __align__(16) _Float16 xtb[16][XSTRIDE]; // LN'd xt, f16
    __shared__ float stats[8][16][2];

    const int tid  = threadIdx.x;
    const int w    = tid >> 6;
    const int lane = tid & 63;
    const int l15  = lane & 15;
    const int quad = lane >> 4;
    const int s0   = blockIdx.x * 2;
    const float k0 = (float)s0, k1 = (float)(s0 + 1);

    // ---- stage x into xsb (f16, rows r = sl*8+b), coalesced float4 reads
    {
        const float4* seq4 = (const float4*)seq;
        #pragma unroll
        for (int u = 0; u < 2; ++u) {
            int v  = tid + 512 * u;          // float4 index 0..1023
            int sl = v >> 9;
            int rm = v & 511;
            int b  = rm >> 6, j4 = rm & 63;
            float4 x = seq4[((size_t)b * SS + s0 + sl) * 64 + j4];
            half2t* dst = (half2t*)&xsb[sl * 8 + b][4 * j4];
            dst[0] = pkrtz(x.x, x.y);
            dst[1] = pkrtz(x.z, x.w);
        }
    }

    // ---- residual in registers: res[t][reg] for (sl=quad>>1, b=(quad*4+reg)&7)
    float res[2][4];
    {
        const int sl = quad >> 1;
        #pragma unroll
        for (int t = 0; t < 2; ++t) {
            int col = 16 * (2 * w + t) + l15;
            #pragma unroll
            for (int reg = 0; reg < 4; ++reg) {
                int b = (quad * 4 + reg) & 7;
                res[t][reg] = seq[((size_t)b * SS + s0 + sl) * DD + col];
            }
        }
    }
    __syncthreads();

    #pragma unroll 1
    for (int layer = 0; layer < 2; ++layer) {
        const float* M  = layer ? M2  : M1;
        const float* P  = layer ? P2  : P1;
        const float* g  = layer ? g2  : g1;
        const float* be = layer ? be2 : be1;
        const char*  lbase = ws + (size_t)layer * LAYER_BYTES;
        const half8*  Mtab = (const half8*)lbase;
        const half8*  Ptab = (const half8*)(lbase + PTAB_OFF);
        const float4* Itab = (const float4*)(lbase + ITAB_OFF);

        // ======== phase A: xt = x @ M^T (f16 MFMA), depth-1 Mtab prefetch
        float4v acc1[2];
        acc1[0] = (float4v){0.f, 0.f, 0.f, 0.f};
        acc1[1] = (float4v){0.f, 0.f, 0.f, 0.f};

        if (TABS) {
            half8 mc0 = Mtab[(0 * 16 + 2 * w) * 64 + lane];
            half8 mc1 = Mtab[(0 * 16 + 2 * w + 1) * 64 + lane];
            half8 ac  = *(const half8*)&xsb[l15][quad * 8];
            #pragma unroll
            for (int kt = 0; kt < 8; ++kt) {
                half8 mn0, mn1, an;
                if (kt < 7) {
                    mn0 = Mtab[((kt + 1) * 16 + 2 * w) * 64 + lane];
                    mn1 = Mtab[((kt + 1) * 16 + 2 * w + 1) * 64 + lane];
                    an  = *(const half8*)&xsb[l15][(kt + 1) * 32 + quad * 8];
                }
                acc1[0] = __builtin_amdgcn_mfma_f32_16x16x32_f16(ac, mc0, acc1[0], 0, 0, 0);
                acc1[1] = __builtin_amdgcn_mfma_f32_16x16x32_f16(ac, mc1, acc1[1], 0, 0, 0);
                if (kt < 7) { mc0 = mn0; mc1 = mn1; ac = an; }
            }
        } else {
            #pragma unroll 2
            for (int kt = 0; kt < 8; ++kt) {
                half8 a = *(const half8*)&xsb[l15][kt * 32 + quad * 8];
                #pragma unroll
                for (int t = 0; t < 2; ++t) {
                    int n = 16 * (2 * w + t) + l15;
                    const float4* Mr = (const float4*)M +
                        ((size_t)n * 64 + kt * 8 + quad * 2);
                    float4 m0 = Mr[0], m1 = Mr[1];
                    hu bb;
                    bb.h2[0] = pkrtz(m0.x, m0.y);
                    bb.h2[1] = pkrtz(m0.z, m0.w);
                    bb.h2[2] = pkrtz(m1.x, m1.y);
                    bb.h2[3] = pkrtz(m1.z, m1.w);
                    acc1[t] = __builtin_amdgcn_mfma_f32_16x16x32_f16(a, bb.h, acc1[t], 0, 0, 0);
                }
            }
        }

        // ======== LayerNorm in C-register layout (row m = quad*4+reg)
        {
            #pragma unroll
            for (int reg = 0; reg < 4; ++reg) {
                float sm = acc1[0][reg] + acc1[1][reg];
                float sq = fmaf(acc1[0][reg], acc1[0][reg], acc1[1][reg] * acc1[1][reg]);
                #pragma unroll
                for (int off = 1; off < 16; off <<= 1) {
                    sm += __shfl_xor(sm, off, 64);
                    sq += __shfl_xor(sq, off, 64);
                }
                if (l15 == 0) {
                    stats[w][quad * 4 + reg][0] = sm;
                    stats[w][quad * 4 + reg][1] = sq;
                }
            }
        }
        __syncthreads();
        {
            float mu[4], rs[4];
            #pragma unroll
            for (int reg = 0; reg < 4; ++reg) {
                int m = quad * 4 + reg;
                float sm = 0.f, sq = 0.f;
                #pragma unroll
                for (int ww = 0; ww < 8; ++ww) {
                    sm += stats[ww][m][0];
                    sq += stats[ww][m][1];
                }
                float mm = sm * (1.f / DD);
                mu[reg] = mm;
                rs[reg] = rsqrtf(sq * (1.f / DD) - mm * mm + 1e-5f);
            }
            #pragma unroll
            for (int t = 0; t < 2; ++t) {
                int col = 16 * (2 * w + t) + l15;
                float gv = g[col], bv = be[col];
                #pragma unroll
                for (int reg = 0; reg < 4; ++reg) {
                    float v = fmaf((acc1[t][reg] - mu[reg]) * rs[reg], gv, bv);
                    xtb[quad * 4 + reg][col] = (_Float16)v;
                }
            }
        }
        __syncthreads();   // xtb ready for phase B

        // ======== phase B: Nk = xt @ W_s^T, depth-1 Ptab/Itab/a prefetch
        float4v accS[2][2];
        #pragma unroll
        for (int sl = 0; sl < 2; ++sl)
            #pragma unroll
            for (int t = 0; t < 2; ++t) accS[sl][t] = (float4v){0.f, 0.f, 0.f, 0.f};

        if (TABS) {
            hu     pc0, pc1;
            float4 ic00, ic01, ic10, ic11;
            half8  ac;
            {
                int gi0 = (2 * w) * 64 + lane;
                int gi1 = gi0 + 64;
                pc0.h = Ptab[gi0]; ic00 = Itab[2 * gi0]; ic01 = Itab[2 * gi0 + 1];
                pc1.h = Ptab[gi1]; ic10 = Itab[2 * gi1]; ic11 = Itab[2 * gi1 + 1];
                ac = *(const half8*)&xtb[l15][quad * 8];
            }
            #pragma unroll
            for (int kt = 0; kt < 8; ++kt) {
                hu     pn0, pn1;
                float4 in00, in01, in10, in11;
                half8  an;
                if (kt < 7) {
                    int gi0 = ((kt + 1) * 16 + 2 * w) * 64 + lane;
                    int gi1 = gi0 + 64;
                    pn0.h = Ptab[gi0]; in00 = Itab[2 * gi0]; in01 = Itab[2 * gi0 + 1];
                    pn1.h = Ptab[gi1]; in10 = Itab[2 * gi1]; in11 = Itab[2 * gi1 + 1];
                    an = *(const half8*)&xtb[l15][(kt + 1) * 32 + quad * 8];
                }
                pb_comp(ac, pc0, ic00, ic01, k0, k1, accS[0][0], accS[1][0]);
                pb_comp(ac, pc1, ic10, ic11, k0, k1, accS[0][1], accS[1][1]);
                if (kt < 7) {
                    pc0 = pn0; ic00 = in00; ic01 = in01;
                    pc1 = pn1; ic10 = in10; ic11 = in11;
                    ac = an;
                }
            }
        } else {
            #pragma unroll 2
            for (int kt = 0; kt < 8; ++kt) {
                half8 a = *(const half8*)&xtb[l15][kt * 32 + quad * 8];
                #pragma unroll
                for (int t = 0; t < 2; ++t) {
                    const int n = 16 * (2 * w + t) + l15;
                    const float p0f = (float)(n * DD + kt * 32 + quad * 8 + 2);
                    const float4* Pr = (const float4*)P +
                        ((size_t)n * 64 + kt * 8 + quad * 2);
                    float4 q0 = Pr[0], q1 = Pr[1];
                    hu pv;
                    pv.h2[0] = pkrtz(q0.x, q0.y);
                    pv.h2[1] = pkrtz(q0.z, q0.w);
                    pv.h2[2] = pkrtz(q1.x, q1.y);
                    pv.h2[3] = pkrtz(q1.z, q1.w);
                    float4 i0, i1;
                    i0.x = __builtin_amdgcn_rcpf(p0f + 0.f);
                    i0.y = __builtin_amdgcn_rcpf(p0f + 1.f);
                    i0.z = __builtin_amdgcn_rcpf(p0f + 2.f);
                    i0.w = __builtin_amdgcn_rcpf(p0f + 3.f);
                    i1.x = __builtin_amdgcn_rcpf(p0f + 4.f);
                    i1.y = __builtin_amdgcn_rcpf(p0f + 5.f);
                    i1.z = __builtin_amdgcn_rcpf(p0f + 6.f);
                    i1.w = __builtin_amdgcn_rcpf(p0f + 7.f);
                    pb_comp(a, pv, i0, i1, k0, k1, accS[0][t], accS[1][t]);
                }
            }
        }

        // ======== epilogue: pick valid s-half per quad, add register residual
        #pragma unroll
        for (int t = 0; t < 2; ++t) {
            int col = 16 * (2 * w + t) + l15;
            float4v av = (quad < 2) ? accS[0][t] : accS[1][t];
            int sl = quad >> 1;
            #pragma unroll
            for (int reg = 0; reg < 4; ++reg) {
                int m = quad * 4 + reg;
                int b = m & 7;
                float val = av[reg] + res[t][reg];
                if (layer == 0) {
                    res[t][reg] = val;             // next layer's residual
                    xsb[m][col] = (_Float16)val;   // next layer's A-matrix
                } else {
                    out[((size_t)b * SS + s0 + sl) * DD + col] = val;
                }
            }
        }
        if (layer == 0) __syncthreads();
    }
}

extern "C" void kernel_launch(void* const* d_in, const int* in_sizes, int n_in,
                              void* d_out, int out_size, void* d_ws, size_t ws_size,
                              hipStream_t stream)
{
    const float* seq = (const float*)d_in[0];
    const float* M1  = (const float*)d_in[1];
    const float* P1  = (const float*)d_in[2];
    const float* g1  = (const float*)d_in[3];
    const float* b1  = (const float*)d_in[4];
    const float* M2  = (const float*)d_in[5];
    const float* P2  = (const float*)d_in[6];
    const float* g2  = (const float*)d_in[7];
    const float* b2  = (const float*)d_in[8];
    float* out = (float*)d_out;

    if (ws_size >= WS_NEEDED) {
        build_tabs<<<64, 256, 0, stream>>>(M1, P1, M2, P2, (char*)d_ws);
        fused_hierddpm<true><<<SS / 2, 512, 0, stream>>>(
            seq, M1, P1, g1, b1, M2, P2, g2, b2, (const char*)d_ws, out);
    } else {
        fused_hierddpm<false><<<SS / 2, 512, 0, stream>>>(
            seq, M1, P1, g1, b1, M2, P2, g2, b2, nullptr, out);
    }
}